// Round 5
// baseline (433.039 us; speedup 1.0000x reference)
//
#include <hip/hip_runtime.h>
#include <math.h>

// ContextCluster, fp32, MI355X gfx950 — round 5.
// Both kernels: NO scalar-pipe weight streams (K$ thrash was the round-4
// stall). Weights live in LDS, read as ds_read_b128 broadcasts.
// K1 grid: blk = e*1024 + bb*64 + fold -> the 8 heads of one region share
// fold%8 -> same XCD -> x region fetched once per XCD (FETCH ~4x down).
// K2: blk = bb*64 + fold -> same XCD as K1's disp writer -> L2-hot reads.

#define TPB 256

__global__ __launch_bounds__(TPB, 3)
void cc_cluster(const float* __restrict__ x,
                const float* __restrict__ Wf, const float* __restrict__ bf,
                const float* __restrict__ Wv, const float* __restrict__ bv,
                const float* __restrict__ salpha, const float* __restrict__ sbeta,
                float* __restrict__ disp)
{
    __shared__ __align__(16) float wlds[6144];   // 24 KB: Wf[e-slice] then Wv[e-slice]
    __shared__ float buf[64*65];                 // 16.6 KB: x chunks, then fs/vsh
    __shared__ __align__(16) float centT[32*4];  // f centers transposed [c][m]
    __shared__ float vcent[4*33];                // v centers [m][c]
    __shared__ float smask[4*64];                // sims then masked sims [m][n]
    __shared__ float aggs[4*33];                 // agg [m][c]
    __shared__ float bsim[64];
    __shared__ int   bidx[64];
    __shared__ int   cnt[4];

    const int t    = threadIdx.x;
    const int lane = t & 63;
    const int wid  = __builtin_amdgcn_readfirstlane(t >> 6);  // 0..3
    const int blk  = blockIdx.x;
    const int e    = blk >> 10;          // head
    const int bb   = (blk >> 6) & 15;    // batch
    const int fold = blk & 63;           // region (fold%8 = XCD)
    const int f1   = fold >> 3, f2 = fold & 7;

    // conv roles: waves 0,1 -> f channels [0..16),[16..32); waves 2,3 -> v
    const bool isF   = (wid < 2);
    const int  cbase = (wid & 1) * 16;
    const int  roff  = (isF ? 0 : 3072) + cbase*96;   // this role's rows in wlds

    // ---- stage weights: 2 x 3072 floats, coalesced float4, 3 per thread ----
    {
        const float4* wfg = (const float4*)(Wf + (size_t)e*32*96);
        const float4* wvg = (const float4*)(Wv + (size_t)e*32*96);
        float4* wf4 = (float4*)wlds;
        float4* wv4 = (float4*)(wlds + 3072);
        #pragma unroll
        for (int i = 0; i < 3; ++i) {
            wf4[i*256 + t] = wfg[i*256 + t];
            wv4[i*256 + t] = wvg[i*256 + t];
        }
    }

    // ---- stage x chunk0 (ch 0..63): thread t -> ch t>>2, rows (t&3)*2,+1 ----
    const int sch = t >> 2;
    const int sw  = (t & 3) * 2;
    const float* xrg = x + (size_t)bb*96*4096 + (size_t)sch*4096
                     + (size_t)(f1*8)*64 + f2*8;
    float4 a0 = *(const float4*)(xrg + sw*64);
    float4 a1 = *(const float4*)(xrg + sw*64 + 4);
    float4 b0 = *(const float4*)(xrg + (sw+1)*64);
    float4 b1 = *(const float4*)(xrg + (sw+1)*64 + 4);
    {
        float* w0 = &buf[sch*65 + sw*8];
        w0[0]=a0.x; w0[1]=a0.y; w0[2]=a0.z; w0[3]=a0.w;
        w0[4]=a1.x; w0[5]=a1.y; w0[6]=a1.z; w0[7]=a1.w;
        float* w1 = &buf[sch*65 + (sw+1)*8];
        w1[0]=b0.x; w1[1]=b0.y; w1[2]=b0.z; w1[3]=b0.w;
        w1[4]=b1.x; w1[5]=b1.y; w1[6]=b1.z; w1[7]=b1.w;
    }
    // prefetch chunk1 (ch 64..95): thread t -> ch 64+(t>>3), row t&7
    const float* xr2 = x + (size_t)bb*96*4096 + (size_t)(64 + (t >> 3))*4096
                     + (size_t)(f1*8 + (t & 7))*64 + f2*8;
    float4 c0 = *(const float4*)(xr2);
    float4 c1 = *(const float4*)(xr2 + 4);

    const float* bsel = isF ? bf : bv;
    float acc[16];
    #pragma unroll
    for (int j = 0; j < 16; ++j) acc[j] = bsel[e*32 + cbase + j];

    __syncthreads();                      // weights + chunk0 ready

    // ---- conv chunk0: k = 0..63, weights via b128 broadcast ----
    #pragma unroll 4
    for (int kg = 0; kg < 16; ++kg) {
        float xv0 = buf[(4*kg+0)*65 + lane];
        float xv1 = buf[(4*kg+1)*65 + lane];
        float xv2 = buf[(4*kg+2)*65 + lane];
        float xv3 = buf[(4*kg+3)*65 + lane];
        #pragma unroll
        for (int j = 0; j < 16; ++j) {
            float4 w4 = *(const float4*)&wlds[roff + j*96 + 4*kg];
            acc[j] = fmaf(w4.x, xv0, acc[j]);
            acc[j] = fmaf(w4.y, xv1, acc[j]);
            acc[j] = fmaf(w4.z, xv2, acc[j]);
            acc[j] = fmaf(w4.w, xv3, acc[j]);
        }
    }
    __syncthreads();                      // chunk0 consumed
    {
        float* w2 = &buf[(t >> 3)*65 + (t & 7)*8];
        w2[0]=c0.x; w2[1]=c0.y; w2[2]=c0.z; w2[3]=c0.w;
        w2[4]=c1.x; w2[5]=c1.y; w2[6]=c1.z; w2[7]=c1.w;
    }
    __syncthreads();                      // chunk1 ready
    #pragma unroll 4
    for (int kg = 0; kg < 8; ++kg) {
        float xv0 = buf[(4*kg+0)*65 + lane];
        float xv1 = buf[(4*kg+1)*65 + lane];
        float xv2 = buf[(4*kg+2)*65 + lane];
        float xv3 = buf[(4*kg+3)*65 + lane];
        #pragma unroll
        for (int j = 0; j < 16; ++j) {
            float4 w4 = *(const float4*)&wlds[roff + j*96 + 64 + 4*kg];
            acc[j] = fmaf(w4.x, xv0, acc[j]);
            acc[j] = fmaf(w4.y, xv1, acc[j]);
            acc[j] = fmaf(w4.z, xv2, acc[j]);
            acc[j] = fmaf(w4.w, xv3, acc[j]);
        }
    }
    __syncthreads();                      // chunk1 consumed; buf now free

    // ---- write f/v points: fs = buf[0..2080), vsh = buf[2080..4160) ----
    {
        float* dst = buf + (isF ? 0 : 2080);
        #pragma unroll
        for (int j = 0; j < 16; ++j) dst[(cbase + j)*65 + lane] = acc[j];
    }
    if (t < 4) cnt[t] = 0;
    __syncthreads();

    // ---- P1: max-pool centers (t<128: f -> centT; t>=128: v -> vcent) ----
    {
        int tt = t & 127;
        int m = tt >> 5, c = tt & 31;
        int pw = m >> 1, ph = m & 1;
        const float* src = (t < 128) ? buf : (buf + 2080);
        float mx = -3.402823466e38f;
        #pragma unroll
        for (int a = 0; a < 4; ++a)
            #pragma unroll
            for (int b2 = 0; b2 < 4; ++b2) {
                int n = (pw*4 + a)*8 + ph*4 + b2;
                mx = fmaxf(mx, src[c*65 + n]);
            }
        if (t < 128) centT[c*4 + m]  = mx;
        else         vcent[m*33 + c] = mx;
    }
    __syncthreads();

    // ---- P2a: sims, all 256 threads: m = wave, n = lane ----
    {
        const int m = wid, n = lane;
        float d = 0.f, pn = 0.f, cn = 0.f;
        #pragma unroll
        for (int c = 0; c < 32; ++c) {
            float fv = buf[c*65 + n];          // fs
            float cm = centT[c*4 + m];         // broadcast read
            d  = fmaf(cm, fv, d);
            pn = fmaf(fv, fv, pn);
            cn = fmaf(cm, cm, cn);
        }
        float ip = 1.f / fmaxf(sqrtf(pn), 1e-12f);
        float ic = 1.f / fmaxf(sqrtf(cn), 1e-12f);
        float z  = sbeta[0] + salpha[0] * (d * ic * ip);
        smask[m*64 + n] = 1.f / (1.f + expf(-z));
    }
    __syncthreads();

    // ---- P2b: argmax + mask (wave 0) ----
    if (t < 64) {
        int n = t;
        float s0 = smask[n], s1 = smask[64+n], s2 = smask[128+n], s3 = smask[192+n];
        int bi = 0; float bv2 = s0;            // first-max tie-break
        if (s1 > bv2) { bv2 = s1; bi = 1; }
        if (s2 > bv2) { bv2 = s2; bi = 2; }
        if (s3 > bv2) { bv2 = s3; bi = 3; }
        bidx[n] = bi; bsim[n] = bv2;
        smask[n]       = (bi==0) ? bv2 : 0.f;
        smask[64 + n]  = (bi==1) ? bv2 : 0.f;
        smask[128 + n] = (bi==2) ? bv2 : 0.f;
        smask[192 + n] = (bi==3) ? bv2 : 0.f;
        atomicAdd(&cnt[bi], 1);
    }
    __syncthreads();

    // ---- P4: aggregate points -> centers ----
    if (t < 128) {
        int m = t >> 5, c = t & 31;
        float s = 0.f;
        const float* sm = &smask[m*64];
        const float* vv = buf + 2080;          // vsh
        #pragma unroll 8
        for (int n2 = 0; n2 < 64; ++n2)
            s = fmaf(vv[c*65 + n2], sm[n2], s);
        aggs[m*33 + c] = (s + vcent[m*33 + c]) / (float)(cnt[m] + 1);
    }
    __syncthreads();

    // ---- P5: dispatch -> disp[bb][e*32+c][fold][n] (coalesced) ----
    {
        float bs = bsim[lane];
        int   bi = bidx[lane];
        size_t obase = (size_t)bb*256*4096 + (size_t)(e*32)*4096
                     + (size_t)fold*64 + lane;
        #pragma unroll
        for (int j = 0; j < 8; ++j) {
            int c = wid*8 + j;
            disp[obase + (size_t)c*4096] = aggs[bi*33 + c] * bs;
        }
    }
}

// K2: out[bb][o][w][h] = sum_c Wp[o][c] * disp[bb][c][fold][n] + bp[o]
// Wp K-chunks in LDS (b128 broadcast); disp direct-global coalesced rows.
// grid 1024 = bb*64 + fold (4 blocks/CU, all co-resident; XCD matches writer).
__global__ __launch_bounds__(TPB, 4)
void cc_proj(const float* __restrict__ disp, const float* __restrict__ Wp,
             const float* __restrict__ bp, float* __restrict__ out)
{
    __shared__ __align__(16) float wch[96*64];   // 24.6 KB: Wp[:, kc:kc+64]
    const int t    = threadIdx.x;
    const int lane = t & 63;
    const int wid  = __builtin_amdgcn_readfirstlane(t >> 6);  // 0..3
    const int fold = blockIdx.x & 63;
    const int bb   = blockIdx.x >> 6;
    const int f1   = fold >> 3, f2 = fold & 7;

    const float* dp = disp + (size_t)bb*256*4096 + (size_t)fold*64 + lane;

    float acc[24];
    #pragma unroll
    for (int j = 0; j < 24; ++j) acc[j] = bp[wid*24 + j];

    for (int kc = 0; kc < 256; kc += 64) {
        if (kc) __syncthreads();              // prev chunk consumed
        // stage Wp[:, kc:kc+64]: 96 rows x 16 float4; 6 float4/thread
        #pragma unroll
        for (int i = 0; i < 6; ++i) {
            int idx = i*256 + t;              // 0..1535
            int oc  = idx >> 4;
            int p   = idx & 15;
            *(float4*)&wch[oc*64 + p*4] =
                *(const float4*)(Wp + (size_t)oc*256 + kc + p*4);
        }
        __syncthreads();                      // chunk ready

        const float* wr = &wch[wid*24*64];
        #pragma unroll 8
        for (int k = 0; k < 64; ++k) {
            float xv = dp[(size_t)(kc + k)*4096];
            const float* wk = wr + (k & ~3);
            int kk = k & 3;
            #pragma unroll
            for (int j = 0; j < 24; ++j)
                acc[j] = fmaf(wk[j*64 + kk], xv, acc[j]);
        }
    }

    // out pixel: w = f1*8 + n/8, h = f2*8 + n%8
    size_t obase = (size_t)bb*96*4096 + (size_t)(f1*8 + (lane >> 3))*64
                 + f2*8 + (lane & 7);
    #pragma unroll
    for (int j = 0; j < 24; ++j)
        out[obase + (size_t)(wid*24 + j)*4096] = acc[j];
}

extern "C" void kernel_launch(void* const* d_in, const int* in_sizes, int n_in,
                              void* d_out, int out_size, void* d_ws, size_t ws_size,
                              hipStream_t stream) {
    (void)in_sizes; (void)n_in; (void)out_size; (void)ws_size;
    float* disp = (float*)d_ws;   // 16*256*4096 floats = 64 MiB
    cc_cluster<<<dim3(8192), dim3(TPB), 0, stream>>>(
        (const float*)d_in[0],  // x
        (const float*)d_in[1],  // Wf
        (const float*)d_in[2],  // bf
        (const float*)d_in[3],  // Wv
        (const float*)d_in[4],  // bv
        (const float*)d_in[7],  // sim_alpha
        (const float*)d_in[8],  // sim_beta
        disp);
    cc_proj<<<dim3(1024), dim3(TPB), 0, stream>>>(
        disp,
        (const float*)d_in[5],  // Wp
        (const float*)d_in[6],  // bp
        (float*)d_out);
}